// Round 4
// baseline (695.726 us; speedup 1.0000x reference)
//
#include <hip/hip_runtime.h>

#define NN 100000
#define NE 3200000
#define HC 16

typedef int iv4 __attribute__((ext_vector_type(4)));

// Native fp32 global atomic add, fire-and-forget (no-return => no sc0, no wait).
// Plain atomicAdd(float*) can lower to a CAS retry loop (denormal semantics);
// under ~32-way same-address contention that would serialize on full memory
// round trips. global_atomic_add_f32 executes memory-side.
__device__ __forceinline__ void gfadd(float* a, float v) {
    asm volatile("global_atomic_add_f32 %0, %1, off"
                 :: "v"(a), "v"(v) : "memory");
}
// Fire-and-forget atomics are untracked by the compiler: drain before s_endpgm
// so the dispatch's end-of-pipe can't retire a wave with unissued traffic.
__device__ __forceinline__ void drain_vm() {
    asm volatile("s_waitcnt vmcnt(0)" ::: "memory");
}

// ---------- pass 1: degree count (3.2M u32 atomics, ~32-way avg contention) ----------

__global__ __launch_bounds__(256) void a_deg(const int* __restrict__ dst,
                                             unsigned* __restrict__ deg) {
    int i = (blockIdx.x * 256 + threadIdx.x) * 4;     // NE % 1024 == 0, no tail
    iv4 d = *(const iv4*)(dst + i);
    atomicAdd(&deg[d.x], 1u);
    atomicAdd(&deg[d.y], 1u);
    atomicAdd(&deg[d.z], 1u);
    atomicAdd(&deg[d.w], 1u);
}

// ---------- pass 2: dinv, p = dinv*x, t seeded with self-loop contribution ----------

__global__ __launch_bounds__(256) void a_node1(const float* __restrict__ x,
                                               const unsigned* __restrict__ deg,
                                               float* __restrict__ dinv,
                                               float* __restrict__ p,
                                               float* __restrict__ t) {
    int i = blockIdx.x * 256 + threadIdx.x;
    if (i < NN) {
        float di = rsqrtf((float)(deg[i] + 1u));      // +1 self-loop
        dinv[i] = di;
        float pi = di * x[i];
        p[i] = pi;
        t[i] = pi;                                    // self-loop seed
    }
}

// ---------- pass 3: layer-1 scatter: t[dst] += p[src] ----------

__global__ __launch_bounds__(256) void a_sc1(const int* __restrict__ src,
                                             const int* __restrict__ dst,
                                             const float* __restrict__ p,
                                             float* __restrict__ t) {
    int i = (blockIdx.x * 256 + threadIdx.x) * 4;
    iv4 s = *(const iv4*)(src + i);
    iv4 d = *(const iv4*)(dst + i);
    float p0 = p[s.x], p1 = p[s.y], p2 = p[s.z], p3 = p[s.w];
    gfadd(&t[d.x], p0);
    gfadd(&t[d.y], p1);
    gfadd(&t[d.z], p2);
    gfadd(&t[d.w], p3);
    drain_vm();
}

// ---------- pass 4: fused MLP per node -> g; seed out with self-loop g ----------

__global__ __launch_bounds__(256) void a_node2(const float* __restrict__ dinv,
                                               const float* __restrict__ t,
                                               const float* __restrict__ W1,
                                               const float* __restrict__ b1,
                                               const float* __restrict__ W2,
                                               float2* __restrict__ g,
                                               float2* __restrict__ out) {
    int i = blockIdx.x * 256 + threadIdx.x;
    if (i < NN) {
        float di = dinv[i];
        float s = di * t[i];
        float g0 = 0.f, g1 = 0.f;
#pragma unroll
        for (int c = 0; c < HC; ++c) {
            float h = fmaxf(fmaf(s, W1[c], b1[c]), 0.f);
            g0 = fmaf(h, W2[2 * c], g0);
            g1 = fmaf(h, W2[2 * c + 1], g1);
        }
        float2 gv = make_float2(di * g0, di * g1);
        g[i] = gv;
        out[i] = gv;                                  // self-loop seed
    }
}

// ---------- pass 5: layer-2 scatter: out[dst] += g[src]  (2 fp atomics/edge) ----------

__global__ __launch_bounds__(256) void a_sc2(const int* __restrict__ src,
                                             const int* __restrict__ dst,
                                             const float2* __restrict__ g,
                                             float* __restrict__ out) {
    int i = (blockIdx.x * 256 + threadIdx.x) * 4;
    iv4 s = *(const iv4*)(src + i);
    iv4 d = *(const iv4*)(dst + i);
    float2 v0 = g[s.x], v1 = g[s.y], v2 = g[s.z], v3 = g[s.w];
    gfadd(&out[2 * d.x],     v0.x);
    gfadd(&out[2 * d.x + 1], v0.y);
    gfadd(&out[2 * d.y],     v1.x);
    gfadd(&out[2 * d.y + 1], v1.y);
    gfadd(&out[2 * d.z],     v2.x);
    gfadd(&out[2 * d.z + 1], v2.y);
    gfadd(&out[2 * d.w],     v3.x);
    gfadd(&out[2 * d.w + 1], v3.y);
    drain_vm();
}

// ---------- pass 6: final scale + bias ----------

__global__ __launch_bounds__(256) void a_out(const float* __restrict__ dinv,
                                             const float* __restrict__ b2,
                                             float* __restrict__ out) {
    int i = blockIdx.x * 256 + threadIdx.x;
    if (i < NN) {
        float di = dinv[i];
        out[2 * i]     = fmaf(di, out[2 * i],     b2[0]);
        out[2 * i + 1] = fmaf(di, out[2 * i + 1], b2[1]);
    }
}

extern "C" void kernel_launch(void* const* d_in, const int* in_sizes, int n_in,
                              void* d_out, int out_size, void* d_ws, size_t ws_size,
                              hipStream_t stream) {
    const float* x  = (const float*)d_in[0];
    const int* ei   = (const int*)d_in[1];
    const int* src  = ei;
    const int* dst  = ei + NE;
    const float* W1 = (const float*)d_in[2];
    const float* b1 = (const float*)d_in[3];
    const float* W2 = (const float*)d_in[4];
    const float* b2 = (const float*)d_in[5];

    size_t need = 0;
    auto carve = [&](size_t bytes) { size_t o = need; need += (bytes + 255) & ~(size_t)255; return o; };
    size_t o_deg  = carve((size_t)NN * 4);
    size_t o_dinv = carve((size_t)NN * 4);
    size_t o_p    = carve((size_t)NN * 4);
    size_t o_t    = carve((size_t)NN * 4);
    size_t o_g    = carve((size_t)NN * 8);
    (void)need;

    char* ws = (char*)d_ws;
    unsigned* deg = (unsigned*)(ws + o_deg);
    float* dinv   = (float*)(ws + o_dinv);
    float* p      = (float*)(ws + o_p);
    float* t      = (float*)(ws + o_t);
    float2* g     = (float2*)(ws + o_g);
    float* out    = (float*)d_out;

    const int GE = NE / 4 / 256;          // 3125, exact
    const int GN = (NN + 255) / 256;      // 391

    hipMemsetAsync(deg, 0, (size_t)NN * 4, stream);
    a_deg  <<<GE, 256, 0, stream>>>(dst, deg);
    a_node1<<<GN, 256, 0, stream>>>(x, deg, dinv, p, t);
    a_sc1  <<<GE, 256, 0, stream>>>(src, dst, p, t);
    a_node2<<<GN, 256, 0, stream>>>(dinv, t, W1, b1, W2, g, (float2*)out);
    a_sc2  <<<GE, 256, 0, stream>>>(src, dst, g, out);
    a_out  <<<GN, 256, 0, stream>>>(dinv, b2, out);
}

// Round 6
// 168.949 us; speedup vs baseline: 4.1180x; 4.1180x over previous
//
#include <hip/hip_runtime.h>

#define NN 100000
#define NE 3200000
#define HC 16

#define BKT_BITS 7
#define BKT_NODES 128                 // nodes per bucket
#define NB 782                        // ceil(NN / 128) buckets
#define CHUNK_S 8192                  // edges per sort chunk
#define NCH 391                       // ceil(NE / CHUNK_S)
#define MCAP 5120                     // per-bucket region capacity (max bucket ~4350)

typedef unsigned uv4 __attribute__((ext_vector_type(4)));
typedef int      iv4 __attribute__((ext_vector_type(4)));

// Native LDS float atomic add (fire-and-forget). Plain atomicAdd(float*) on LDS
// lowers to a CAS retry loop. __syncthreads() drains lgkmcnt, ordering these.
// (This exact formulation passed correctness in round 2.)
__device__ __forceinline__ void ds_fadd(float* addr, float v) {
    asm volatile("ds_add_f32 %0, %1"
                 :: "v"((unsigned)(unsigned long long)addr), "v"(v) : "memory");
}

// ---------- pass 1: per-chunk LDS counting sort by dst-bucket, coalesced run write-out
// into per-bucket global regions claimed via one global atomicAdd per (chunk,bucket).
// word = (src << 7) | (dst & 127). (Unchanged from round 3 — proven.)

__global__ __launch_bounds__(512) void k_sortbin(const int* __restrict__ src,
                                                 const int* __restrict__ dst,
                                                 unsigned* __restrict__ gcur,
                                                 unsigned* __restrict__ regions) {
    __shared__ unsigned h[NB];            // hist -> excl-scan -> scatter cursor -> end
    __shared__ unsigned exc[NB];          // exclusive starts (snapshot)
    __shared__ int gofs[NB];              // global_base - lds_start per bucket
    __shared__ unsigned sorted[CHUNK_S];  // 32 KB
    __shared__ unsigned short bkid[CHUNK_S]; // 16 KB: bucket id per sorted slot
    __shared__ unsigned wsum[8];
    int tid = threadIdx.x, c = blockIdx.x;
    int b0 = c * CHUNK_S;
    int e1 = min(b0 + CHUNK_S, NE);
    int cnt = e1 - b0;                    // 8192 or 5120 (both %4 == 0)

    for (int j = tid; j < NB; j += 512) h[j] = 0;
    __syncthreads();

    iv4 dreg[4], sreg[4];
    int nit = 0;
    for (int v = b0 + tid * 4; v + 3 < e1; v += 2048) {
        iv4 d4 = *(const iv4*)(dst + v);
        iv4 s4 = *(const iv4*)(src + v);
        dreg[nit] = d4; sreg[nit] = s4; ++nit;
        atomicAdd(&h[((unsigned)d4.x) >> BKT_BITS], 1u);
        atomicAdd(&h[((unsigned)d4.y) >> BKT_BITS], 1u);
        atomicAdd(&h[((unsigned)d4.z) >> BKT_BITS], 1u);
        atomicAdd(&h[((unsigned)d4.w) >> BKT_BITS], 1u);
    }
    __syncthreads();

    // exclusive scan of h[0..NB), 2 cells/thread (1024 >= 782)
    int i0 = tid * 2;
    unsigned v0 = (i0 + 0 < NB) ? h[i0 + 0] : 0;
    unsigned v1 = (i0 + 1 < NB) ? h[i0 + 1] : 0;
    unsigned lsum = v0 + v1;
    unsigned sc = lsum;
#pragma unroll
    for (int off = 1; off < 64; off <<= 1) {
        unsigned u = __shfl_up(sc, off, 64);
        if ((tid & 63) >= off) sc += u;
    }
    int wave = tid >> 6;
    if ((tid & 63) == 63) wsum[wave] = sc;
    __syncthreads();
    unsigned wpre = 0;
    for (int w = 0; w < wave; ++w) wpre += wsum[w];
    unsigned excl = wpre + sc - lsum;
    if (i0 + 0 < NB) { h[i0 + 0] = excl;      exc[i0 + 0] = excl; }
    if (i0 + 1 < NB) { h[i0 + 1] = excl + v0; exc[i0 + 1] = excl + v0; }
    __syncthreads();

    // scatter-sort into LDS (h becomes per-bucket cursor)
    int it = 0;
    for (int v = b0 + tid * 4; v + 3 < e1; v += 2048, ++it) {
        iv4 d4 = dreg[it];
        iv4 s4 = sreg[it];
        {   unsigned d = (unsigned)d4.x, s = (unsigned)s4.x, bk = d >> BKT_BITS;
            unsigned pos = atomicAdd(&h[bk], 1u);
            sorted[pos] = (s << BKT_BITS) | (d & (BKT_NODES - 1)); bkid[pos] = (unsigned short)bk; }
        {   unsigned d = (unsigned)d4.y, s = (unsigned)s4.y, bk = d >> BKT_BITS;
            unsigned pos = atomicAdd(&h[bk], 1u);
            sorted[pos] = (s << BKT_BITS) | (d & (BKT_NODES - 1)); bkid[pos] = (unsigned short)bk; }
        {   unsigned d = (unsigned)d4.z, s = (unsigned)s4.z, bk = d >> BKT_BITS;
            unsigned pos = atomicAdd(&h[bk], 1u);
            sorted[pos] = (s << BKT_BITS) | (d & (BKT_NODES - 1)); bkid[pos] = (unsigned short)bk; }
        {   unsigned d = (unsigned)d4.w, s = (unsigned)s4.w, bk = d >> BKT_BITS;
            unsigned pos = atomicAdd(&h[bk], 1u);
            sorted[pos] = (s << BKT_BITS) | (d & (BKT_NODES - 1)); bkid[pos] = (unsigned short)bk; }
    }
    __syncthreads();

    // claim per-bucket global runs; precompute (global_base - lds_start)
    for (int j = tid; j < NB; j += 512) {
        unsigned len = h[j] - exc[j];
        if (len)
            gofs[j] = (int)((unsigned)j * MCAP + atomicAdd(&gcur[j], len)) - (int)exc[j];
    }
    __syncthreads();

    // write-out: consecutive lanes write consecutive addresses within each run
    for (int j = tid; j < cnt; j += 512)
        regions[(unsigned)(gofs[bkid[j]] + j)] = sorted[j];
}

// ---------- pass 2: per-bucket degree -> dinv, p (direct region read, no staging) ----------

__global__ __launch_bounds__(512) void k_phaseA(const unsigned* __restrict__ regions,
                                                const unsigned* __restrict__ gcur,
                                                const float* __restrict__ x,
                                                float* __restrict__ dinv,
                                                float* __restrict__ p) {
    __shared__ unsigned cnt[BKT_NODES];
    int tid = threadIdx.x, b = blockIdx.x;
    if (tid < BKT_NODES) cnt[tid] = 0;
    __syncthreads();

    unsigned sz = gcur[b];
    unsigned sz4 = sz & ~3u;
    const unsigned* r = regions + (size_t)b * MCAP;
    for (unsigned j = (unsigned)tid * 4; j < sz4; j += 2048) {
        uv4 e = *(const uv4*)(r + j);
        atomicAdd(&cnt[e.x & (BKT_NODES - 1)], 1u);
        atomicAdd(&cnt[e.y & (BKT_NODES - 1)], 1u);
        atomicAdd(&cnt[e.z & (BKT_NODES - 1)], 1u);
        atomicAdd(&cnt[e.w & (BKT_NODES - 1)], 1u);
    }
    for (unsigned j = sz4 + (unsigned)tid; j < sz; j += 512)
        atomicAdd(&cnt[r[j] & (BKT_NODES - 1)], 1u);
    __syncthreads();

    int node = b * BKT_NODES + tid;
    if (tid < BKT_NODES && node < NN) {
        float di = rsqrtf((float)(cnt[tid] + 1u));   // +1 self-loop
        dinv[node] = di;
        p[node] = di * x[node];
    }
}

// ---------- pass 3: layer-1 aggregate (direct region read, gather p, ds_add) + MLP ----------

__global__ __launch_bounds__(512) void k_phaseB(const unsigned* __restrict__ regions,
                                                const unsigned* __restrict__ gcur,
                                                const float* __restrict__ dinv,
                                                const float* __restrict__ p,
                                                const float* __restrict__ W1,
                                                const float* __restrict__ b1,
                                                const float* __restrict__ W2,
                                                float2* __restrict__ g) {
    __shared__ float acc[BKT_NODES];
    int tid = threadIdx.x, b = blockIdx.x;
    if (tid < BKT_NODES) acc[tid] = 0.f;
    __syncthreads();

    unsigned sz = gcur[b];
    unsigned sz4 = sz & ~3u;
    const unsigned* r = regions + (size_t)b * MCAP;
    for (unsigned j = (unsigned)tid * 4; j < sz4; j += 2048) {
        uv4 e = *(const uv4*)(r + j);
        float p0 = p[e.x >> BKT_BITS];
        float p1 = p[e.y >> BKT_BITS];
        float p2 = p[e.z >> BKT_BITS];
        float p3 = p[e.w >> BKT_BITS];
        ds_fadd(&acc[e.x & (BKT_NODES - 1)], p0);
        ds_fadd(&acc[e.y & (BKT_NODES - 1)], p1);
        ds_fadd(&acc[e.z & (BKT_NODES - 1)], p2);
        ds_fadd(&acc[e.w & (BKT_NODES - 1)], p3);
    }
    for (unsigned j = sz4 + (unsigned)tid; j < sz; j += 512) {
        unsigned e = r[j];
        ds_fadd(&acc[e & (BKT_NODES - 1)], p[e >> BKT_BITS]);
    }
    __syncthreads();

    int node = b * BKT_NODES + tid;
    if (tid < BKT_NODES && node < NN) {
        float di = dinv[node];
        float sf = di * (acc[tid] + p[node]);        // + self-loop
        float g0 = 0.f, g1 = 0.f;
#pragma unroll
        for (int c = 0; c < HC; ++c) {
            float h = fmaxf(fmaf(sf, W1[c], b1[c]), 0.f);
            g0 = fmaf(h, W2[2 * c], g0);
            g1 = fmaf(h, W2[2 * c + 1], g1);
        }
        g[node] = make_float2(di * g0, di * g1);
    }
}

// ---------- pass 4: layer-2 aggregate (direct region read, gather g, ds_add x2) -> out ----------

__global__ __launch_bounds__(512) void k_phaseC(const unsigned* __restrict__ regions,
                                                const unsigned* __restrict__ gcur,
                                                const float* __restrict__ dinv,
                                                const float2* __restrict__ g,
                                                const float* __restrict__ b2,
                                                float2* __restrict__ out) {
    __shared__ float accx[BKT_NODES];
    __shared__ float accy[BKT_NODES];
    int tid = threadIdx.x, b = blockIdx.x;
    if (tid < BKT_NODES) { accx[tid] = 0.f; accy[tid] = 0.f; }
    __syncthreads();

    unsigned sz = gcur[b];
    unsigned sz4 = sz & ~3u;
    const unsigned* r = regions + (size_t)b * MCAP;
    for (unsigned j = (unsigned)tid * 4; j < sz4; j += 2048) {
        uv4 e = *(const uv4*)(r + j);
        float2 v0 = g[e.x >> BKT_BITS];
        float2 v1 = g[e.y >> BKT_BITS];
        float2 v2 = g[e.z >> BKT_BITS];
        float2 v3 = g[e.w >> BKT_BITS];
        ds_fadd(&accx[e.x & (BKT_NODES - 1)], v0.x);
        ds_fadd(&accy[e.x & (BKT_NODES - 1)], v0.y);
        ds_fadd(&accx[e.y & (BKT_NODES - 1)], v1.x);
        ds_fadd(&accy[e.y & (BKT_NODES - 1)], v1.y);
        ds_fadd(&accx[e.z & (BKT_NODES - 1)], v2.x);
        ds_fadd(&accy[e.z & (BKT_NODES - 1)], v2.y);
        ds_fadd(&accx[e.w & (BKT_NODES - 1)], v3.x);
        ds_fadd(&accy[e.w & (BKT_NODES - 1)], v3.y);
    }
    for (unsigned j = sz4 + (unsigned)tid; j < sz; j += 512) {
        unsigned e = r[j];
        float2 v = g[e >> BKT_BITS];
        ds_fadd(&accx[e & (BKT_NODES - 1)], v.x);
        ds_fadd(&accy[e & (BKT_NODES - 1)], v.y);
    }
    __syncthreads();

    int node = b * BKT_NODES + tid;
    if (tid < BKT_NODES && node < NN) {
        float di = dinv[node];
        float2 gv = g[node];
        float ax = accx[tid] + gv.x;                 // + self-loop
        float ay = accy[tid] + gv.y;
        out[node] = make_float2(fmaf(di, ax, b2[0]), fmaf(di, ay, b2[1]));
    }
}

// ---------- fallback: atomic-scatter path (small ws) ----------

__global__ __launch_bounds__(256) void f_deg(const int* __restrict__ dst,
                                             unsigned int* __restrict__ deg, int E) {
    int i = blockIdx.x * blockDim.x + threadIdx.x;
    if (i < E) atomicAdd(&deg[dst[i]], 1u);
}
__global__ __launch_bounds__(256) void f_node1(const float* __restrict__ x,
                                               const unsigned int* __restrict__ deg,
                                               float* __restrict__ dinv, float* __restrict__ p,
                                               float* __restrict__ t, int N) {
    int i = blockIdx.x * blockDim.x + threadIdx.x;
    if (i < N) {
        float di = rsqrtf((float)(deg[i] + 1u));
        dinv[i] = di; float pi = di * x[i]; p[i] = pi; t[i] = pi;
    }
}
__global__ __launch_bounds__(256) void f_scatter1(const int* __restrict__ src,
                                                  const int* __restrict__ dst,
                                                  const float* __restrict__ p,
                                                  float* __restrict__ t, int E) {
    int i = blockIdx.x * blockDim.x + threadIdx.x;
    if (i < E) atomicAdd(&t[dst[i]], p[src[i]]);
}
__global__ __launch_bounds__(256) void f_node2(const float* __restrict__ dinv,
                                               const float* __restrict__ t,
                                               const float* __restrict__ W1,
                                               const float* __restrict__ b1,
                                               const float* __restrict__ W2,
                                               float2* __restrict__ g,
                                               float2* __restrict__ acc, int N) {
    int i = blockIdx.x * blockDim.x + threadIdx.x;
    if (i < N) {
        float di = dinv[i]; float s = di * t[i];
        float g0 = 0.f, g1 = 0.f;
#pragma unroll
        for (int c = 0; c < HC; ++c) {
            float h = fmaxf(fmaf(s, W1[c], b1[c]), 0.f);
            g0 = fmaf(h, W2[2 * c], g0); g1 = fmaf(h, W2[2 * c + 1], g1);
        }
        float2 gv = make_float2(di * g0, di * g1);
        g[i] = gv; acc[i] = gv;
    }
}
__global__ __launch_bounds__(256) void f_scatter2(const int* __restrict__ src,
                                                  const int* __restrict__ dst,
                                                  const float2* __restrict__ g,
                                                  float* __restrict__ acc, int E) {
    int i = blockIdx.x * blockDim.x + threadIdx.x;
    if (i < E) {
        int s = src[i], d = dst[i];
        float2 gv = g[s];
        atomicAdd(&acc[2 * d], gv.x);
        atomicAdd(&acc[2 * d + 1], gv.y);
    }
}
__global__ __launch_bounds__(256) void f_out(const float* __restrict__ dinv,
                                             const float* __restrict__ b2,
                                             float* __restrict__ out, int N) {
    int i = blockIdx.x * blockDim.x + threadIdx.x;
    if (i < N) {
        float di = dinv[i];
        out[2 * i]     = fmaf(di, out[2 * i],     b2[0]);
        out[2 * i + 1] = fmaf(di, out[2 * i + 1], b2[1]);
    }
}

extern "C" void kernel_launch(void* const* d_in, const int* in_sizes, int n_in,
                              void* d_out, int out_size, void* d_ws, size_t ws_size,
                              hipStream_t stream) {
    const float* x  = (const float*)d_in[0];
    const int* ei   = (const int*)d_in[1];
    const int* src  = ei;
    const int* dst  = ei + NE;
    const float* W1 = (const float*)d_in[2];
    const float* b1 = (const float*)d_in[3];
    const float* W2 = (const float*)d_in[4];
    const float* b2 = (const float*)d_in[5];

    const int BT = 256;
    const int gridE = (NE + BT - 1) / BT;
    const int gridN = (NN + BT - 1) / BT;

    size_t need = 0;
    auto carve = [&](size_t bytes) { size_t o = need; need += (bytes + 255) & ~(size_t)255; return o; };
    size_t o_gcur = carve((size_t)NB * 4);
    size_t o_dinv = carve((size_t)NN * 4);
    size_t o_p    = carve((size_t)NN * 4);
    size_t o_g    = carve((size_t)NN * 8);
    size_t o_reg  = carve((size_t)NB * MCAP * 4);

    if (ws_size >= need) {
        char* ws = (char*)d_ws;
        unsigned* gcur   = (unsigned*)(ws + o_gcur);
        float*    dinv   = (float*)(ws + o_dinv);
        float*    p      = (float*)(ws + o_p);
        float2*   g      = (float2*)(ws + o_g);
        unsigned* regions= (unsigned*)(ws + o_reg);

        hipMemsetAsync(gcur, 0, (size_t)NB * 4, stream);
        k_sortbin<<<NCH, 512, 0, stream>>>(src, dst, gcur, regions);
        k_phaseA <<<NB, 512, 0, stream>>>(regions, gcur, x, dinv, p);
        k_phaseB <<<NB, 512, 0, stream>>>(regions, gcur, dinv, p, W1, b1, W2, g);
        k_phaseC <<<NB, 512, 0, stream>>>(regions, gcur, dinv, g, b2, (float2*)d_out);
    } else {
        float* out = (float*)d_out;
        char* ws = (char*)d_ws;
        unsigned int* deg = (unsigned int*)ws;
        float* dinv = (float*)(ws + 1 * sizeof(float) * NN);
        float* p    = (float*)(ws + 2 * sizeof(float) * NN);
        float* t    = (float*)(ws + 3 * sizeof(float) * NN);
        float2* g   = (float2*)(ws + 4 * sizeof(float) * NN);

        hipMemsetAsync(deg, 0, NN * sizeof(unsigned int), stream);
        f_deg<<<gridE, BT, 0, stream>>>(dst, deg, NE);
        f_node1<<<gridN, BT, 0, stream>>>(x, deg, dinv, p, t, NN);
        f_scatter1<<<gridE, BT, 0, stream>>>(src, dst, p, t, NE);
        f_node2<<<gridN, BT, 0, stream>>>(dinv, t, W1, b1, W2, g, (float2*)out, NN);
        f_scatter2<<<gridE, BT, 0, stream>>>(src, dst, g, out, NE);
        f_out<<<gridN, BT, 0, stream>>>(dinv, b2, out, NN);
    }
}

// Round 7
// 137.095 us; speedup vs baseline: 5.0748x; 1.2324x over previous
//
#include <hip/hip_runtime.h>

#define NN 100000
#define NE 3200000
#define HC 16

#define BKT_BITS 7
#define BKT_NODES 128                 // nodes per bucket
#define NB 782                        // ceil(NN / 128) buckets
#define CHUNK_S 8192                  // edges per sort chunk
#define NCH 391                       // ceil(NE / CHUNK_S)
#define MCAP 5120                     // per-bucket region capacity (max bucket ~4350)
#define COFS 130                      // cofsg row stride (129 offsets + pad)

typedef unsigned uv4 __attribute__((ext_vector_type(4)));
typedef int      iv4 __attribute__((ext_vector_type(4)));

// ---------- pass 1: per-chunk LDS counting sort by dst-bucket, coalesced run write-out
// into per-bucket global regions claimed via one global atomicAdd per (chunk,bucket).
// word = (src << 7) | (dst & 127). (Byte-identical to the round-3 proven version.)

__global__ __launch_bounds__(512) void k_sortbin(const int* __restrict__ src,
                                                 const int* __restrict__ dst,
                                                 unsigned* __restrict__ gcur,
                                                 unsigned* __restrict__ regions) {
    __shared__ unsigned h[NB];            // hist -> excl-scan -> scatter cursor -> end
    __shared__ unsigned exc[NB];          // exclusive starts (snapshot)
    __shared__ int gofs[NB];              // global_base - lds_start per bucket
    __shared__ unsigned sorted[CHUNK_S];  // 32 KB
    __shared__ unsigned short bkid[CHUNK_S]; // 16 KB: bucket id per sorted slot
    __shared__ unsigned wsum[8];
    int tid = threadIdx.x, c = blockIdx.x;
    int b0 = c * CHUNK_S;
    int e1 = min(b0 + CHUNK_S, NE);
    int cnt = e1 - b0;                    // 8192 or 5120 (both %4 == 0)

    for (int j = tid; j < NB; j += 512) h[j] = 0;
    __syncthreads();

    iv4 dreg[4], sreg[4];
    int nit = 0;
    for (int v = b0 + tid * 4; v + 3 < e1; v += 2048) {
        iv4 d4 = *(const iv4*)(dst + v);
        iv4 s4 = *(const iv4*)(src + v);
        dreg[nit] = d4; sreg[nit] = s4; ++nit;
        atomicAdd(&h[((unsigned)d4.x) >> BKT_BITS], 1u);
        atomicAdd(&h[((unsigned)d4.y) >> BKT_BITS], 1u);
        atomicAdd(&h[((unsigned)d4.z) >> BKT_BITS], 1u);
        atomicAdd(&h[((unsigned)d4.w) >> BKT_BITS], 1u);
    }
    __syncthreads();

    // exclusive scan of h[0..NB), 2 cells/thread (1024 >= 782)
    int i0 = tid * 2;
    unsigned v0 = (i0 + 0 < NB) ? h[i0 + 0] : 0;
    unsigned v1 = (i0 + 1 < NB) ? h[i0 + 1] : 0;
    unsigned lsum = v0 + v1;
    unsigned sc = lsum;
#pragma unroll
    for (int off = 1; off < 64; off <<= 1) {
        unsigned u = __shfl_up(sc, off, 64);
        if ((tid & 63) >= off) sc += u;
    }
    int wave = tid >> 6;
    if ((tid & 63) == 63) wsum[wave] = sc;
    __syncthreads();
    unsigned wpre = 0;
    for (int w = 0; w < wave; ++w) wpre += wsum[w];
    unsigned excl = wpre + sc - lsum;
    if (i0 + 0 < NB) { h[i0 + 0] = excl;      exc[i0 + 0] = excl; }
    if (i0 + 1 < NB) { h[i0 + 1] = excl + v0; exc[i0 + 1] = excl + v0; }
    __syncthreads();

    // scatter-sort into LDS (h becomes per-bucket cursor)
    int it = 0;
    for (int v = b0 + tid * 4; v + 3 < e1; v += 2048, ++it) {
        iv4 d4 = dreg[it];
        iv4 s4 = sreg[it];
        {   unsigned d = (unsigned)d4.x, s = (unsigned)s4.x, bk = d >> BKT_BITS;
            unsigned pos = atomicAdd(&h[bk], 1u);
            sorted[pos] = (s << BKT_BITS) | (d & (BKT_NODES - 1)); bkid[pos] = (unsigned short)bk; }
        {   unsigned d = (unsigned)d4.y, s = (unsigned)s4.y, bk = d >> BKT_BITS;
            unsigned pos = atomicAdd(&h[bk], 1u);
            sorted[pos] = (s << BKT_BITS) | (d & (BKT_NODES - 1)); bkid[pos] = (unsigned short)bk; }
        {   unsigned d = (unsigned)d4.z, s = (unsigned)s4.z, bk = d >> BKT_BITS;
            unsigned pos = atomicAdd(&h[bk], 1u);
            sorted[pos] = (s << BKT_BITS) | (d & (BKT_NODES - 1)); bkid[pos] = (unsigned short)bk; }
        {   unsigned d = (unsigned)d4.w, s = (unsigned)s4.w, bk = d >> BKT_BITS;
            unsigned pos = atomicAdd(&h[bk], 1u);
            sorted[pos] = (s << BKT_BITS) | (d & (BKT_NODES - 1)); bkid[pos] = (unsigned short)bk; }
    }
    __syncthreads();

    // claim per-bucket global runs; precompute (global_base - lds_start)
    for (int j = tid; j < NB; j += 512) {
        unsigned len = h[j] - exc[j];
        if (len)
            gofs[j] = (int)((unsigned)j * MCAP + atomicAdd(&gcur[j], len)) - (int)exc[j];
    }
    __syncthreads();

    // write-out: consecutive lanes write consecutive addresses within each run
    for (int j = tid; j < cnt; j += 512)
        regions[(unsigned)(gofs[bkid[j]] + j)] = sorted[j];
}

// ---------- pass 2: per-bucket degree -> CSR offsets + dinv, p (512 thr) ----------

__global__ __launch_bounds__(512) void k_degcsr(const unsigned* __restrict__ regions,
                                                const unsigned* __restrict__ gcur,
                                                const float* __restrict__ x,
                                                unsigned short* __restrict__ cofsg,
                                                float* __restrict__ dinv,
                                                float* __restrict__ p) {
    __shared__ unsigned cnt[BKT_NODES];
    __shared__ unsigned wsA;
    int tid = threadIdx.x, b = blockIdx.x;
    if (tid < BKT_NODES) cnt[tid] = 0;
    __syncthreads();

    unsigned sz = gcur[b];
    unsigned sz4 = sz & ~3u;
    const unsigned* r = regions + (size_t)b * MCAP;
    for (unsigned j = (unsigned)tid * 4; j < sz4; j += 2048) {
        uv4 e = *(const uv4*)(r + j);
        atomicAdd(&cnt[e.x & (BKT_NODES - 1)], 1u);
        atomicAdd(&cnt[e.y & (BKT_NODES - 1)], 1u);
        atomicAdd(&cnt[e.z & (BKT_NODES - 1)], 1u);
        atomicAdd(&cnt[e.w & (BKT_NODES - 1)], 1u);
    }
    for (unsigned j = sz4 + (unsigned)tid; j < sz; j += 512)
        atomicAdd(&cnt[r[j] & (BKT_NODES - 1)], 1u);
    __syncthreads();

    // inclusive scan of cnt[128] -> cofsg[b][1..128]; cofsg[b][0] = 0
    unsigned cv = (tid < BKT_NODES) ? cnt[tid] : 0u;
    unsigned csc = cv;
#pragma unroll
    for (int off = 1; off < 64; off <<= 1) {
        unsigned u = __shfl_up(csc, off, 64);
        if ((tid & 63) >= off) csc += u;
    }
    if (tid == 63) wsA = csc;
    __syncthreads();
    if (tid < BKT_NODES) {
        unsigned incl = csc + ((tid >= 64) ? wsA : 0u);
        cofsg[(size_t)b * COFS + tid + 1] = (unsigned short)incl;
    }
    if (tid == 0) cofsg[(size_t)b * COFS + 0] = 0;

    int node = b * BKT_NODES + tid;
    if (tid < BKT_NODES && node < NN) {
        float di = rsqrtf((float)(cnt[tid] + 1u));   // +1 self-loop
        dinv[node] = di;
        p[node] = di * x[node];
    }
}

// ---------- pass 3: layer-1 — LDS scatter-sort by node, register segment sums
//            (4 thr/node), fused MLP. NO global write-back (agg2 re-sorts). ----------

__global__ __launch_bounds__(512) void k_agg1(const unsigned* __restrict__ regions,
                                              const unsigned* __restrict__ gcur,
                                              const unsigned short* __restrict__ cofsg,
                                              const float* __restrict__ dinv,
                                              const float* __restrict__ p,
                                              const float* __restrict__ W1,
                                              const float* __restrict__ b1,
                                              const float* __restrict__ W2,
                                              float2* __restrict__ g) {
    __shared__ unsigned short cof[BKT_NODES + 2];
    __shared__ unsigned cur[BKT_NODES];
    __shared__ unsigned se[MCAP];
    __shared__ float part[512];
    int tid = threadIdx.x, b = blockIdx.x;
    if (tid < BKT_NODES + 1) cof[tid] = cofsg[(size_t)b * COFS + tid];
    __syncthreads();
    if (tid < BKT_NODES) cur[tid] = cof[tid];
    __syncthreads();

    unsigned sz = gcur[b];
    unsigned sz4 = sz & ~3u;
    const unsigned* m = regions + (size_t)b * MCAP;
    for (unsigned j = (unsigned)tid * 4; j < sz4; j += 2048) {
        uv4 e = *(const uv4*)(m + j);
        { unsigned w = e.x; se[atomicAdd(&cur[w & (BKT_NODES - 1)], 1u)] = w >> BKT_BITS; }
        { unsigned w = e.y; se[atomicAdd(&cur[w & (BKT_NODES - 1)], 1u)] = w >> BKT_BITS; }
        { unsigned w = e.z; se[atomicAdd(&cur[w & (BKT_NODES - 1)], 1u)] = w >> BKT_BITS; }
        { unsigned w = e.w; se[atomicAdd(&cur[w & (BKT_NODES - 1)], 1u)] = w >> BKT_BITS; }
    }
    for (unsigned j = sz4 + (unsigned)tid; j < sz; j += 512) {
        unsigned w = m[j];
        se[atomicAdd(&cur[w & (BKT_NODES - 1)], 1u)] = w >> BKT_BITS;
    }
    __syncthreads();

    int nl = tid >> 2, q = tid & 3;                 // 4 threads per node
    unsigned o0 = cof[nl], o1 = cof[nl + 1];
    unsigned len = o1 - o0;
    unsigned s = o0 + ((len * q) >> 2);
    unsigned e = o0 + ((len * (q + 1)) >> 2);
    float sum = 0.f;
    unsigned i = s;
    for (; i + 3 < e; i += 4) {
        unsigned a0 = se[i], a1 = se[i + 1], a2 = se[i + 2], a3 = se[i + 3];
        float x0 = p[a0], x1 = p[a1], x2 = p[a2], x3 = p[a3];
        sum += (x0 + x1) + (x2 + x3);
    }
    for (; i < e; ++i) sum += p[se[i]];
    part[tid] = sum;
    __syncthreads();

    if (q == 0) {
        int node = b * BKT_NODES + nl;
        if (node < NN) {
            float di = dinv[node];
            float sf = di * (part[tid] + part[tid + 1] + part[tid + 2] + part[tid + 3]
                             + p[node]);            // + self-loop
            float g0 = 0.f, g1 = 0.f;
#pragma unroll
            for (int c = 0; c < HC; ++c) {
                float h = fmaxf(fmaf(sf, W1[c], b1[c]), 0.f);
                g0 = fmaf(h, W2[2 * c], g0);
                g1 = fmaf(h, W2[2 * c + 1], g1);
            }
            g[node] = make_float2(di * g0, di * g1);
        }
    }
}

// ---------- pass 4: layer-2 — same local re-sort, float2 register segment sums ----------

__global__ __launch_bounds__(512) void k_agg2(const unsigned* __restrict__ regions,
                                              const unsigned* __restrict__ gcur,
                                              const unsigned short* __restrict__ cofsg,
                                              const float* __restrict__ dinv,
                                              const float2* __restrict__ g,
                                              const float* __restrict__ b2,
                                              float2* __restrict__ out) {
    __shared__ unsigned short cof[BKT_NODES + 2];
    __shared__ unsigned cur[BKT_NODES];
    __shared__ unsigned se[MCAP];
    __shared__ float2 part[512];
    int tid = threadIdx.x, b = blockIdx.x;
    if (tid < BKT_NODES + 1) cof[tid] = cofsg[(size_t)b * COFS + tid];
    __syncthreads();
    if (tid < BKT_NODES) cur[tid] = cof[tid];
    __syncthreads();

    unsigned sz = gcur[b];
    unsigned sz4 = sz & ~3u;
    const unsigned* m = regions + (size_t)b * MCAP;
    for (unsigned j = (unsigned)tid * 4; j < sz4; j += 2048) {
        uv4 e = *(const uv4*)(m + j);
        { unsigned w = e.x; se[atomicAdd(&cur[w & (BKT_NODES - 1)], 1u)] = w >> BKT_BITS; }
        { unsigned w = e.y; se[atomicAdd(&cur[w & (BKT_NODES - 1)], 1u)] = w >> BKT_BITS; }
        { unsigned w = e.z; se[atomicAdd(&cur[w & (BKT_NODES - 1)], 1u)] = w >> BKT_BITS; }
        { unsigned w = e.w; se[atomicAdd(&cur[w & (BKT_NODES - 1)], 1u)] = w >> BKT_BITS; }
    }
    for (unsigned j = sz4 + (unsigned)tid; j < sz; j += 512) {
        unsigned w = m[j];
        se[atomicAdd(&cur[w & (BKT_NODES - 1)], 1u)] = w >> BKT_BITS;
    }
    __syncthreads();

    int nl = tid >> 2, q = tid & 3;                 // 4 threads per node
    unsigned o0 = cof[nl], o1 = cof[nl + 1];
    unsigned len = o1 - o0;
    unsigned s = o0 + ((len * q) >> 2);
    unsigned e = o0 + ((len * (q + 1)) >> 2);
    float sx = 0.f, sy = 0.f;
    unsigned i = s;
    for (; i + 3 < e; i += 4) {
        unsigned a0 = se[i], a1 = se[i + 1], a2 = se[i + 2], a3 = se[i + 3];
        float2 v0 = g[a0], v1 = g[a1], v2 = g[a2], v3 = g[a3];
        sx += (v0.x + v1.x) + (v2.x + v3.x);
        sy += (v0.y + v1.y) + (v2.y + v3.y);
    }
    for (; i < e; ++i) { float2 v = g[se[i]]; sx += v.x; sy += v.y; }
    part[tid] = make_float2(sx, sy);
    __syncthreads();

    if (q == 0) {
        int node = b * BKT_NODES + nl;
        if (node < NN) {
            float di = dinv[node];
            float2 me = g[node];
            float ax = part[tid].x + part[tid + 1].x + part[tid + 2].x + part[tid + 3].x + me.x;
            float ay = part[tid].y + part[tid + 1].y + part[tid + 2].y + part[tid + 3].y + me.y;
            out[node] = make_float2(fmaf(di, ax, b2[0]), fmaf(di, ay, b2[1]));
        }
    }
}

// ---------- fallback: atomic-scatter path (small ws) ----------

__global__ __launch_bounds__(256) void f_deg(const int* __restrict__ dst,
                                             unsigned int* __restrict__ deg, int E) {
    int i = blockIdx.x * blockDim.x + threadIdx.x;
    if (i < E) atomicAdd(&deg[dst[i]], 1u);
}
__global__ __launch_bounds__(256) void f_node1(const float* __restrict__ x,
                                               const unsigned int* __restrict__ deg,
                                               float* __restrict__ dinv, float* __restrict__ p,
                                               float* __restrict__ t, int N) {
    int i = blockIdx.x * blockDim.x + threadIdx.x;
    if (i < N) {
        float di = rsqrtf((float)(deg[i] + 1u));
        dinv[i] = di; float pi = di * x[i]; p[i] = pi; t[i] = pi;
    }
}
__global__ __launch_bounds__(256) void f_scatter1(const int* __restrict__ src,
                                                  const int* __restrict__ dst,
                                                  const float* __restrict__ p,
                                                  float* __restrict__ t, int E) {
    int i = blockIdx.x * blockDim.x + threadIdx.x;
    if (i < E) atomicAdd(&t[dst[i]], p[src[i]]);
}
__global__ __launch_bounds__(256) void f_node2(const float* __restrict__ dinv,
                                               const float* __restrict__ t,
                                               const float* __restrict__ W1,
                                               const float* __restrict__ b1,
                                               const float* __restrict__ W2,
                                               float2* __restrict__ g,
                                               float2* __restrict__ acc, int N) {
    int i = blockIdx.x * blockDim.x + threadIdx.x;
    if (i < N) {
        float di = dinv[i]; float s = di * t[i];
        float g0 = 0.f, g1 = 0.f;
#pragma unroll
        for (int c = 0; c < HC; ++c) {
            float h = fmaxf(fmaf(s, W1[c], b1[c]), 0.f);
            g0 = fmaf(h, W2[2 * c], g0); g1 = fmaf(h, W2[2 * c + 1], g1);
        }
        float2 gv = make_float2(di * g0, di * g1);
        g[i] = gv; acc[i] = gv;
    }
}
__global__ __launch_bounds__(256) void f_scatter2(const int* __restrict__ src,
                                                  const int* __restrict__ dst,
                                                  const float2* __restrict__ g,
                                                  float* __restrict__ acc, int E) {
    int i = blockIdx.x * blockDim.x + threadIdx.x;
    if (i < E) {
        int s = src[i], d = dst[i];
        float2 gv = g[s];
        atomicAdd(&acc[2 * d], gv.x);
        atomicAdd(&acc[2 * d + 1], gv.y);
    }
}
__global__ __launch_bounds__(256) void f_out(const float* __restrict__ dinv,
                                             const float* __restrict__ b2,
                                             float* __restrict__ out, int N) {
    int i = blockIdx.x * blockDim.x + threadIdx.x;
    if (i < N) {
        float di = dinv[i];
        out[2 * i]     = fmaf(di, out[2 * i],     b2[0]);
        out[2 * i + 1] = fmaf(di, out[2 * i + 1], b2[1]);
    }
}

extern "C" void kernel_launch(void* const* d_in, const int* in_sizes, int n_in,
                              void* d_out, int out_size, void* d_ws, size_t ws_size,
                              hipStream_t stream) {
    const float* x  = (const float*)d_in[0];
    const int* ei   = (const int*)d_in[1];
    const int* src  = ei;
    const int* dst  = ei + NE;
    const float* W1 = (const float*)d_in[2];
    const float* b1 = (const float*)d_in[3];
    const float* W2 = (const float*)d_in[4];
    const float* b2 = (const float*)d_in[5];

    const int BT = 256;
    const int gridE = (NE + BT - 1) / BT;
    const int gridN = (NN + BT - 1) / BT;

    size_t need = 0;
    auto carve = [&](size_t bytes) { size_t o = need; need += (bytes + 255) & ~(size_t)255; return o; };
    size_t o_gcur = carve((size_t)NB * 4);
    size_t o_cofs = carve((size_t)NB * COFS * 2);
    size_t o_dinv = carve((size_t)NN * 4);
    size_t o_p    = carve((size_t)NN * 4);
    size_t o_g    = carve((size_t)NN * 8);
    size_t o_reg  = carve((size_t)NB * MCAP * 4);

    if (ws_size >= need) {
        char* ws = (char*)d_ws;
        unsigned* gcur        = (unsigned*)(ws + o_gcur);
        unsigned short* cofsg = (unsigned short*)(ws + o_cofs);
        float*    dinv   = (float*)(ws + o_dinv);
        float*    p      = (float*)(ws + o_p);
        float2*   g      = (float2*)(ws + o_g);
        unsigned* regions= (unsigned*)(ws + o_reg);

        hipMemsetAsync(gcur, 0, (size_t)NB * 4, stream);
        k_sortbin<<<NCH, 512, 0, stream>>>(src, dst, gcur, regions);
        k_degcsr <<<NB, 512, 0, stream>>>(regions, gcur, x, cofsg, dinv, p);
        k_agg1   <<<NB, 512, 0, stream>>>(regions, gcur, cofsg, dinv, p, W1, b1, W2, g);
        k_agg2   <<<NB, 512, 0, stream>>>(regions, gcur, cofsg, dinv, g, b2, (float2*)d_out);
    } else {
        float* out = (float*)d_out;
        char* ws = (char*)d_ws;
        unsigned int* deg = (unsigned int*)ws;
        float* dinv = (float*)(ws + 1 * sizeof(float) * NN);
        float* p    = (float*)(ws + 2 * sizeof(float) * NN);
        float* t    = (float*)(ws + 3 * sizeof(float) * NN);
        float2* g   = (float2*)(ws + 4 * sizeof(float) * NN);

        hipMemsetAsync(deg, 0, NN * sizeof(unsigned int), stream);
        f_deg<<<gridE, BT, 0, stream>>>(dst, deg, NE);
        f_node1<<<gridN, BT, 0, stream>>>(x, deg, dinv, p, t, NN);
        f_scatter1<<<gridE, BT, 0, stream>>>(src, dst, p, t, NE);
        f_node2<<<gridN, BT, 0, stream>>>(dinv, t, W1, b1, W2, g, (float2*)out, NN);
        f_scatter2<<<gridE, BT, 0, stream>>>(src, dst, g, out, NE);
        f_out<<<gridN, BT, 0, stream>>>(dinv, b2, out, NN);
    }
}